// Round 21
// baseline (517.310 us; speedup 1.0000x reference)
//
#include <hip/hip_runtime.h>
#include <hip/hip_bf16.h>
#include <stdint.h>

// Problem constants (QuantizedLinear_15985868276124)
#define IN_F   4096                 // bytes per i8 row == elements
#define OUT_F  11008
#define M_TOK  8192

typedef __attribute__((ext_vector_type(4)))  int int32x4;
typedef __attribute__((ext_vector_type(16))) int int32x16;

// ---------- kernel 1: merged prep — quantize x rows AND W rows ----------
__global__ __launch_bounds__(256) void k_prep(
        const float* __restrict__ x,
        const int* __restrict__ codes,
        const float* __restrict__ codebooks,
        const float* __restrict__ scales,
        signed char* __restrict__ Xq, float* __restrict__ sx,
        signed char* __restrict__ Wq, float* __restrict__ sw) {
    __shared__ float cb[4096];
    __shared__ float red[256];
    int t = threadIdx.x;

    if (blockIdx.x < M_TOK) {
        int r = blockIdx.x;
        const float4* xr = (const float4*)(x + (size_t)r * IN_F) + t * 4;
        float4 v0 = xr[0], v1 = xr[1], v2 = xr[2], v3 = xr[3];
        float m = 0.f;
#define MX4(v) m = fmaxf(m, fmaxf(fmaxf(fabsf(v.x), fabsf(v.y)), fmaxf(fabsf(v.z), fabsf(v.w))))
        MX4(v0); MX4(v1); MX4(v2); MX4(v3);
        red[t] = m; __syncthreads();
        for (int s = 128; s > 0; s >>= 1) {
            if (t < s) red[t] = fmaxf(red[t], red[t + s]);
            __syncthreads();
        }
        float rm = fmaxf(red[0], 1e-8f);
        if (t == 0) sx[r] = rm / 127.f;
        float inv = 127.f / rm;
        union { signed char c[16]; uint4 u; } pk;
#define Q4(v, o) pk.c[o] = (signed char)__float2int_rn(v.x * inv);            \
                 pk.c[o+1] = (signed char)__float2int_rn(v.y * inv);          \
                 pk.c[o+2] = (signed char)__float2int_rn(v.z * inv);          \
                 pk.c[o+3] = (signed char)__float2int_rn(v.w * inv)
        Q4(v0, 0); Q4(v1, 4); Q4(v2, 8); Q4(v3, 12);
        *(uint4*)(Xq + (size_t)r * IN_F + t * 16) = pk.u;
    } else {
        int o = blockIdx.x - M_TOK;
        {
            const float4* cbg = (const float4*)codebooks;
            float4* cbl = (float4*)cb;
#pragma unroll
            for (int i = 0; i < 4; ++i) cbl[t + i * 256] = cbg[t + i * 256];
        }
        __syncthreads();
        const int2* cp = (const int2*)codes + (size_t)o * 512 + t * 2;
        int2 c0 = cp[0], c1 = cp[1];
        float e[16]; float m = 0.f;
#pragma unroll
        for (int j = 0; j < 8; ++j) {
            e[j]     = cb[c0.x * 8 + j] + cb[2048 + c0.y * 8 + j];
            e[8 + j] = cb[c1.x * 8 + j] + cb[2048 + c1.y * 8 + j];
        }
#pragma unroll
        for (int j = 0; j < 16; ++j) m = fmaxf(m, fabsf(e[j]));
        red[t] = m; __syncthreads();
        for (int s = 128; s > 0; s >>= 1) {
            if (t < s) red[t] = fmaxf(red[t], red[t + s]);
            __syncthreads();
        }
        float rm = fmaxf(red[0], 1e-8f);
        if (t == 0) sw[o] = scales[o] * rm / 127.f;
        float inv = 127.f / rm;
        union { signed char c[16]; uint4 u; } pk;
#pragma unroll
        for (int j = 0; j < 16; ++j) pk.c[j] = (signed char)__float2int_rn(e[j] * inv);
        *(uint4*)(Wq + (size_t)o * IN_F + t * 16) = pk.u;
    }
}

// ---------- kernel 2: 256x256 i8 GEMM, 32x32x32 MFMA ----------
// R21: mfma_i32_32x32x32_i8 — halves MFMA instruction count (32 vs 64 per
// wave-K-tile at equal FLOPs) and raises the pipe ceiling (4404 vs 3944
// TOPS). Fragments: A/B = 4 dwords; lane l holds row/col l&31, k-offset
// (l>>5)*16 within the kk*32B block -> LDS chunk (kk*2+(l>>5)) ^ (l&7)
// (conflict-free, same family as 16x16 pattern). C/D (m74/m101): col =
// lane&31, row = (reg&3)+8*(reg>>2)+4*(lane>>5). Wave tile 128x64:
// acc[4m][2n] x16 = 128 AGPR. R16's proven 2-region staging protocol.
// No setprio (R18). 8 waves (2Mx4N), launch_bounds(512,2).

#define BARRIER() __builtin_amdgcn_s_barrier()
#define VMW(n)    asm volatile("s_waitcnt vmcnt(" #n ")")

#define GL16(gp, lp) __builtin_amdgcn_global_load_lds(                        \
    (const __attribute__((address_space(1))) void*)(gp),                      \
    (__attribute__((address_space(3))) void*)(lp), 16, 0, 0)

__global__ __launch_bounds__(512, 2) void k_gemm(
        const signed char* __restrict__ A,   // [M_TOK][IN_F] i8
        const signed char* __restrict__ B,   // [OUT_F][IN_F] i8 (B^T layout)
        const float* __restrict__ sx,        // [M_TOK]
        const float* __restrict__ sw,        // [OUT_F]
        const float* __restrict__ bias,
        float* __restrict__ out) {
    __shared__ signed char lA0[256 * 128];   // 32 KiB each
    __shared__ signed char lA1[256 * 128];
    __shared__ signed char lB0[256 * 128];
    __shared__ signed char lB1[256 * 128];

    const int tid = threadIdx.x;
    const int l = tid & 63;
    const int w = tid >> 6;            // wave 0..7
    const int wm = w >> 2, wn = w & 3; // 2 x 4 wave grid; wave tile 128x64

    // T1: bijective XCD swizzle. grid 1376 = 8 XCD * (4 row-chunks * 43 cols)
    int lid = blockIdx.x;
    int xcd = lid & 7, j = lid >> 3;
    int bx = j >> 2;                   // col block 0..42
    int by = (xcd << 2) + (j & 3);     // row block 0..31
    const int rowBase = by * 256;
    const int colBase = bx * 256;

    // ---- staging addressing (swizzle on GLOBAL source; LDS linear)
    const int srow = w * 8 + (l >> 3);
    const int scol = ((l & 7) ^ ((l >> 3) & 7)) << 4;   // byte offset in row
    const signed char* gA = A + (size_t)(rowBase + srow) * IN_F + scol;
    const signed char* gB = B + (size_t)(colBase + srow) * IN_F + scol;
    signed char* lA0w = &lA0[w * 8 * 128];
    signed char* lA1w = &lA1[w * 8 * 128];
    signed char* lB0w = &lB0[w * 8 * 128];
    signed char* lB1w = &lB1[w * 8 * 128];

    // stage half of K-tile t into buffer P: H=0 -> A rows, H=1 -> B rows (4 GL16)
#define STAGEH_(P, t, H) do {                                                 \
    const signed char* _g = ((H) ? gB : gA) + (size_t)(t) * 128;              \
    signed char* _l = ((H) ? lB##P##w : lA##P##w);                            \
    GL16(_g,                       _l);                                       \
    GL16(_g +  64 * IN_F,          _l +  64 * 128);                           \
    GL16(_g + 128 * IN_F,          _l + 128 * 128);                           \
    GL16(_g + 192 * IN_F,          _l + 192 * 128);                           \
} while (0)

    // ---- fragment reads (32x32 layout): lane l -> row/col l&31,
    // chunk16 = (kk*2 + (l>>5)) ^ (l&7)
    const int fr32 = l & 31, hi = l >> 5;
    const int cho0 = (((0 * 2 + hi) ^ (l & 7)) << 4);
    const int cho1 = (((1 * 2 + hi) ^ (l & 7)) << 4);
    const int cho2 = (((2 * 2 + hi) ^ (l & 7)) << 4);
    const int cho3 = (((3 * 2 + hi) ^ (l & 7)) << 4);
#define CHO(kk) ((kk) == 0 ? cho0 : (kk) == 1 ? cho1 : (kk) == 2 ? cho2 : cho3)
    const char* rowA0 = (const char*)&lA0[(wm * 128 + fr32) * 128];
    const char* rowA1 = (const char*)&lA1[(wm * 128 + fr32) * 128];
    const char* rowB0 = (const char*)&lB0[(wn * 64 + fr32) * 128];
    const char* rowB1 = (const char*)&lB1[(wn * 64 + fr32) * 128];
#define LDA_(P, m, kk) (*(const int32x4*)(rowA##P + (m) * 4096 + CHO(kk)))
#define LDB_(P, n, kk) (*(const int32x4*)(rowB##P + (n) * 4096 + CHO(kk)))

    int32x16 acc[4][2] = {};
    int32x4 ar[2][4];   // 2 m-frags (time-shared m01/m23) x 4 kk
    int32x4 br[2][4];   // 2 n-frags x 4 kk

    // 16 MFMA: 2m x 2n x 4kk accumulating into acc[M0..M0+1][*]
#define QUAD32(M0) do {                                                       \
    _Pragma("unroll") for (int mm = 0; mm < 2; ++mm)                          \
    _Pragma("unroll") for (int nn = 0; nn < 2; ++nn)                          \
    _Pragma("unroll") for (int kk = 0; kk < 4; ++kk)                          \
        acc[(M0) + mm][nn] = __builtin_amdgcn_mfma_i32_32x32x32_i8(           \
            ar[mm][kk], br[nn][kk], acc[(M0) + mm][nn], 0, 0, 0);             \
} while (0)

#define RD_AR01(P) do {                                                       \
    _Pragma("unroll") for (int mm = 0; mm < 2; ++mm)                          \
    _Pragma("unroll") for (int kk = 0; kk < 4; ++kk)                          \
        ar[mm][kk] = LDA_(P, mm, kk);                                         \
} while (0)
#define RD_AR23(P) do {                                                       \
    _Pragma("unroll") for (int mm = 0; mm < 2; ++mm)                          \
    _Pragma("unroll") for (int kk = 0; kk < 4; ++kk)                          \
        ar[mm][kk] = LDA_(P, 2 + mm, kk);                                     \
} while (0)
#define RD_BR(P) do {                                                         \
    _Pragma("unroll") for (int nn = 0; nn < 2; ++nn)                          \
    _Pragma("unroll") for (int kk = 0; kk < 4; ++kk)                          \
        br[nn][kk] = LDB_(P, nn, kk);                                         \
} while (0)

    // prologue: stage t0 A+B (buf0) + t1 B (buf1); VMW(4) retires t0; publish
    STAGEH_(0, 0, 0); STAGEH_(0, 0, 1);
    STAGEH_(1, 1, 1);
    VMW(4); BARRIER();

    // main loop: pairs (e,o) = (0,1)..(28,29); i = 0..14.
    // R1(e): rd ar01+br (buf0); stage oA->buf1;       QUAD32(0); bar
    // R2(e): rd ar23;           stage (e+2)B->buf0;   QUAD32(2); VMW(4); bar [pub o]
    // R3(o): rd ar01+br (buf1); stage (e+2)A->buf0;   QUAD32(0); bar
    // R4(o): rd ar23;           stage (o+2)B->buf1;   QUAD32(2); VMW(4); bar [pub e+2]
    for (int i = 0; i < 15; ++i) {
        int e = 2 * i, o = 2 * i + 1;
        // R1(e)
        RD_AR01(0); RD_BR(0);
        STAGEH_(1, o, 0);
        QUAD32(0); BARRIER();
        // R2(e)
        RD_AR23(0);
        STAGEH_(0, e + 2, 1);
        QUAD32(2);
        VMW(4); BARRIER();                 // publishes tile o
        // R3(o)
        RD_AR01(1); RD_BR(1);
        STAGEH_(0, e + 2, 0);
        QUAD32(0); BARRIER();
        // R4(o)
        RD_AR23(1);
        STAGEH_(1, o + 2, 1);
        QUAD32(2);
        VMW(4); BARRIER();                 // publishes tile e+2
    }

    // tail: pair (30,31). Entering: tile 30 published; 31B outstanding (4).
    RD_AR01(0); RD_BR(0);
    STAGEH_(1, 31, 0);                     // 31A
    QUAD32(0); BARRIER();
    RD_AR23(0);
    QUAD32(2);
    VMW(0); BARRIER();                     // retires + publishes tile 31
    RD_AR01(1); RD_BR(1);
    QUAD32(0); BARRIER();
    RD_AR23(1);
    QUAD32(2);

    // epilogue (32x32 C/D): col = lane&31, row = (reg&3)+8*(reg>>2)+4*(l>>5)
    // out = sx[row]*sw[col]*acc + bias[col]
#pragma unroll
    for (int n = 0; n < 2; ++n) {
        int gcol = colBase + wn * 64 + n * 32 + fr32;
        float swv = sw[gcol];
        float bv = bias[gcol];
#pragma unroll
        for (int m = 0; m < 4; ++m) {
            int rbase = rowBase + wm * 128 + m * 32 + 4 * hi;
#pragma unroll
            for (int r1 = 0; r1 < 4; ++r1) {
                int grow0 = rbase + 8 * r1;
                float4 sx4 = *(const float4*)&sx[grow0];
                out[(size_t)(grow0 + 0) * OUT_F + gcol] = (float)acc[m][n][r1 * 4 + 0] * sx4.x * swv + bv;
                out[(size_t)(grow0 + 1) * OUT_F + gcol] = (float)acc[m][n][r1 * 4 + 1] * sx4.y * swv + bv;
                out[(size_t)(grow0 + 2) * OUT_F + gcol] = (float)acc[m][n][r1 * 4 + 2] * sx4.z * swv + bv;
                out[(size_t)(grow0 + 3) * OUT_F + gcol] = (float)acc[m][n][r1 * 4 + 3] * sx4.w * swv + bv;
            }
        }
    }
}

// ---------- launch ----------
extern "C" void kernel_launch(void* const* d_in, const int* in_sizes, int n_in,
                              void* d_out, int out_size, void* d_ws, size_t ws_size,
                              hipStream_t stream) {
    const float* x         = (const float*)d_in[0];
    const int*   codes     = (const int*)d_in[1];
    const float* codebooks = (const float*)d_in[2];
    const float* scales    = (const float*)d_in[3];
    const float* bias      = (const float*)d_in[4];
    float* out = (float*)d_out;

    // workspace: Wq i8 [OUT_F][IN_F]; Xq i8 [M_TOK][IN_F]; sx; sw (~78.7 MB)
    signed char* Wq = (signed char*)d_ws;
    signed char* Xq = Wq + (size_t)OUT_F * IN_F;
    float* sx = (float*)(Xq + (size_t)M_TOK * IN_F);
    float* sw = sx + M_TOK;

    k_prep<<<M_TOK + OUT_F, 256, 0, stream>>>(x, codes, codebooks, scales,
                                              Xq, sx, Wq, sw);
    // grid: (8192/256) * (11008/256) = 32 * 43 = 1376 blocks, 512 threads
    k_gemm<<<1376, 512, 0, stream>>>(Xq, Wq, sx, sw, bias, out);
}